// Round 3
// baseline (206.038 us; speedup 1.0000x reference)
//
#include <hip/hip_runtime.h>
#include <stdint.h>

#define B_N   1024
#define D_DIM 512
#define H_DIM 512
#define A_DIM 18
#define T_N   64
#define HTILE 256
#define SMB   16      // samples per fc1 block pass
#define NSB   4       // fc1 sample-blocks per task
#define NSB2  8       // head sample-blocks per task

// meta workspace layout (ints): off[0..64] at META_OFF, slist[1024] at META_SLIST
#define META_OFF   0
#define META_SLIST 256
#define META_INTS  2048      // 8 KB reserved before hpre

// Inline task_id dtype detection (int32 vs int64), executed by one full wave.
__device__ __forceinline__ bool taskid_is_int32(const int* raw, int lane) {
    int probe = raw[lane];
    unsigned long long odd = __ballot((lane & 1) && probe != 0);
    return odd != 0ull;
}

// ---------------- K0: bucket task ids once (1 block, 1024 threads) ----------------
// Produces off[T_N+1] (exclusive prefix) and slist (sample indices compacted by
// task). Slot order within a task is irrelevant: every sample's computation is
// independent and written to its own hpre/out rows.
__global__ __launch_bounds__(1024) void bucket_kernel(const int* __restrict__ raw,
                                                      int* __restrict__ meta) {
    __shared__ int cnt[T_N];
    __shared__ int base[T_N];
    __shared__ int flag32;
    int tid = threadIdx.x;
    if (tid < 64) {
        bool is32 = taskid_is_int32(raw, tid);
        if (tid == 0) flag32 = is32 ? 1 : 0;
    }
    if (tid < T_N) cnt[tid] = 0;
    __syncthreads();
    int id = flag32 ? raw[tid] : raw[2 * tid];
    atomicAdd(&cnt[id], 1);
    __syncthreads();
    if (tid < 64) {
        int v = cnt[tid];
        int x = v;
#pragma unroll
        for (int o = 1; o < 64; o <<= 1) {          // inclusive scan, wave 0
            int tv = __shfl_up(x, o);
            if (tid >= o) x += tv;
        }
        int excl = x - v;
        meta[META_OFF + tid] = excl;
        base[tid] = excl;
        if (tid == 63) meta[META_OFF + 64] = x;     // = B_N
    }
    __syncthreads();
    int pos = atomicAdd(&base[id], 1);
    meta[META_SLIST + pos] = tid;
}

// ---------------- K2: fc1 partial GEMM ----------------
// Proven wave layout (round-0): wave covers 256 cols via float4 (hbase=lane*4),
// slots split across waves (sl = wv4 + 4j). v3 changes: samples split across the
// grid (NSB sample-blocks x SMB slots -> 4x more working blocks, one pass per
// sample), w chunk loads register double-buffered, bucketing read from meta.
// Per (sample,col) arithmetic: d ascending single fmaf chain — bit-identical.
template <int KSP>
__global__ __launch_bounds__(256) void fc1_kernel(const float* __restrict__ xs,
                                                  const float* __restrict__ w1,
                                                  const int* __restrict__ meta,
                                                  float* __restrict__ hpre) {
    constexpr int DK = D_DIM / KSP;
    constexpr int NCHUNK = DK / 8;
    int bx    = blockIdx.x;
    int task  = bx % T_N;       // sb-major: the NSB siblings of a task share bx%8 -> same XCD
    int sb    = bx / T_N;
    int htile = blockIdx.y;
    int ksp   = blockIdx.z;
    int tid   = threadIdx.x;
    int lane  = tid & 63;
    int wv4   = tid >> 6;

    int off0 = meta[META_OFF + task];
    int n    = meta[META_OFF + task + 1] - off0;
    if (sb * SMB >= n) return;

    const int* slist = meta + META_SLIST + off0;

    __shared__ __align__(16) float xlds[SMB][DK];

    int hbase = htile * HTILE + lane * 4;
    int d0    = ksp * DK;
    const float* wbase = w1 + ((size_t)task * D_DIM + d0) * H_DIM + hbase;
    float* hout = hpre + (size_t)ksp * ((size_t)B_N * H_DIM);

    for (int sbase = sb * SMB; sbase < n; sbase += NSB * SMB) {
        int ns = min(SMB, n - sbase);

        // stage xs rows (coalesced float4)
        for (int idx = tid; idx < SMB * (DK / 4); idx += 256) {
            int sl = idx / (DK / 4);
            int f  = idx - sl * (DK / 4);
            if (sl < ns) {
                int smp = slist[sbase + sl];
                *(float4*)(&xlds[sl][4 * f]) =
                    *(const float4*)(xs + (size_t)smp * D_DIM + d0 + 4 * f);
            }
        }
        __syncthreads();

        float4 acc[SMB / 4];
#pragma unroll
        for (int j = 0; j < SMB / 4; ++j) acc[j] = make_float4(0.f, 0.f, 0.f, 0.f);

        float4 wva[8], wvb[8];

#define LOADW(buf, cc)                                                        \
        _Pragma("unroll")                                                     \
        for (int u = 0; u < 8; ++u)                                           \
            buf[u] = *(const float4*)(wbase + (size_t)((cc) * 8 + u) * H_DIM);

#define COMPW(buf, cc) do {                                                   \
        _Pragma("unroll")                                                     \
        for (int j = 0; j < SMB / 4; ++j) {                                   \
            int sl = wv4 + 4 * j;                                             \
            if (sl < ns) {                 /* wave-uniform predicate */       \
                const float* xp = &xlds[sl][8 * (cc)];                        \
                float4 xa = *(const float4*)xp;                               \
                float4 xb = *(const float4*)(xp + 4);                         \
                float xv[8] = {xa.x, xa.y, xa.z, xa.w,                        \
                               xb.x, xb.y, xb.z, xb.w};                       \
                _Pragma("unroll")                                             \
                for (int u = 0; u < 8; ++u) {                                 \
                    acc[j].x = fmaf(xv[u], buf[u].x, acc[j].x);               \
                    acc[j].y = fmaf(xv[u], buf[u].y, acc[j].y);               \
                    acc[j].z = fmaf(xv[u], buf[u].z, acc[j].z);               \
                    acc[j].w = fmaf(xv[u], buf[u].w, acc[j].w);               \
                }                                                             \
            }                                                                 \
        }                                                                     \
    } while (0)

        LOADW(wva, 0);
#pragma unroll
        for (int c = 0; c < NCHUNK; ++c) {
            if ((c & 1) == 0) {
                if (c + 1 < NCHUNK) { LOADW(wvb, c + 1); }
                COMPW(wva, c);
            } else {
                if (c + 1 < NCHUNK) { LOADW(wva, c + 1); }
                COMPW(wvb, c);
            }
        }
#undef LOADW
#undef COMPW

#pragma unroll
        for (int j = 0; j < SMB / 4; ++j) {
            int sl = wv4 + 4 * j;
            if (sl < ns) {
                int smp = slist[sbase + sl];
                *(float4*)(hout + (size_t)smp * H_DIM + hbase) = acc[j];
            }
        }
        __syncthreads();
    }
}

// ---------------- threefry2x32, partitionable counter mode, key = (0, 1) --------
// (validated bit-exact — do not touch)
__device__ __forceinline__ uint32_t rotl32(uint32_t x, int r) {
    return (x << r) | (x >> (32 - r));
}

__device__ __forceinline__ uint32_t threefry_bits_part(uint32_t i) {
    uint32_t x0 = 0u;        // i >> 32 for i < 2^32
    uint32_t x1 = i;
    const uint32_t ks0 = 0u, ks1 = 1u, ks2 = 0x1BD11BDAu ^ 0u ^ 1u;
    x0 += ks0; x1 += ks1;
#define TFR(r) { x0 += x1; x1 = rotl32(x1, (r)); x1 ^= x0; }
    TFR(13) TFR(15) TFR(26) TFR(6)
    x0 += ks1; x1 += ks2 + 1u;
    TFR(17) TFR(29) TFR(16) TFR(24)
    x0 += ks2; x1 += ks0 + 2u;
    TFR(13) TFR(15) TFR(26) TFR(6)
    x0 += ks0; x1 += ks1 + 3u;
    TFR(17) TFR(29) TFR(16) TFR(24)
    x0 += ks1; x1 += ks2 + 4u;
    TFR(13) TFR(15) TFR(26) TFR(6)
    x0 += ks2; x1 += ks0 + 5u;
#undef TFR
    return x0 ^ x1;
}

// ---------------- K3: relu + fc2 + log_softmax + gumbel sample ----
// v2: bucketed — block = (task, sample-chunk). 4 waves stage w2[t] ONCE, then
// each wave runs the per-sample math IDENTICALLY to the validated version
// (same shfl pattern, same red g-order, same b1/b2/q order, threefry keyed by
// the ORIGINAL sample index). Uniform round count K per block keeps
// __syncthreads legal; inactive waves compute on s=0 data and don't write.
template <int KSP>
__global__ __launch_bounds__(256) void head_kernel(const int* __restrict__ meta,
                                                   const float* __restrict__ hpre,
                                                   const float* __restrict__ b1,
                                                   const float* __restrict__ w2,
                                                   const float* __restrict__ b2,
                                                   float* __restrict__ out) {
    __shared__ __align__(16) float w2l[H_DIM * A_DIM];   // 36 KB
    __shared__ float red[4][16][A_DIM];
    __shared__ float logits_lds[4][A_DIM];

    int t    = blockIdx.x;
    int y    = blockIdx.y;
    int tid  = threadIdx.x;
    int lane = tid & 63;
    int wv   = tid >> 6;

    int off0 = meta[META_OFF + t];
    int n    = meta[META_OFF + t + 1] - off0;
    if (4 * y >= n) return;                      // uniform block exit
    int K = (n - 4 * y - 1) / 32 + 1;            // uniform rounds per block

    const int* slist = meta + META_SLIST + off0;

    // ---- stage w2[t] into LDS, coalesced: 2304 float4 over 256 threads ----
    const float4* g4 = (const float4*)(w2 + (size_t)t * (H_DIM * A_DIM));
    float4* l4 = (float4*)w2l;
#pragma unroll
    for (int i = 0; i < (H_DIM * A_DIM) / (256 * 4); ++i)   // 9 iters
        l4[i * 256 + tid] = g4[i * 256 + tid];
    __syncthreads();

    for (int rnd = 0; rnd < K; ++rnd) {
        int slot = 4 * y + wv + 32 * rnd;
        bool active = slot < n;
        int s = active ? slist[slot] : 0;

        // ---- h = relu(sum_k partial_k + b1) ----
        float hreg[H_DIM / 64];
#pragma unroll
        for (int kk = 0; kk < H_DIM / 64; ++kk) {
            int h = lane + 64 * kk;
            size_t p = (size_t)s * H_DIM + h;
            float v = b1[(size_t)t * H_DIM + h];
#pragma unroll
            for (int q = 0; q < KSP; ++q)
                v += hpre[(size_t)q * ((size_t)B_N * H_DIM) + p];
            hreg[kk] = fmaxf(v, 0.f);
        }

        // ---- per-lane partial logits from LDS ----
        float la[A_DIM];
#pragma unroll
        for (int a = 0; a < A_DIM; ++a) la[a] = 0.f;
#pragma unroll
        for (int kk = 0; kk < H_DIM / 64; ++kk) {
            int h = lane + 64 * kk;
            const float2* row = (const float2*)&w2l[h * A_DIM];
            float hk = hreg[kk];
#pragma unroll
            for (int a2 = 0; a2 < A_DIM / 2; ++a2) {
                float2 ww = row[a2];
                la[2 * a2]     = fmaf(hk, ww.x, la[2 * a2]);
                la[2 * a2 + 1] = fmaf(hk, ww.y, la[2 * a2 + 1]);
            }
        }

        // ---- reduce 64 partials: shfl_xor(1,2) -> 16 rows -> LDS -> 18-lane sum ----
#pragma unroll
        for (int a = 0; a < A_DIM; ++a) {
            la[a] += __shfl_xor(la[a], 1);
            la[a] += __shfl_xor(la[a], 2);
        }
        if ((lane & 3) == 0) {
            int g = lane >> 2;
#pragma unroll
            for (int a = 0; a < A_DIM; ++a) red[wv][g][a] = la[a];
        }
        __syncthreads();
        if (lane < A_DIM) {
            float sum = b2[(size_t)t * A_DIM + lane];
#pragma unroll
            for (int g = 0; g < 16; ++g) sum += red[wv][g][lane];
            logits_lds[wv][lane] = sum;
        }
        __syncthreads();

        // ---- tail: identical to the validated code ----
        float lg = (lane < A_DIM) ? logits_lds[wv][lane] : -INFINITY;

        float z = -INFINITY;
        if (lane < A_DIM) {
            uint32_t bits = threefry_bits_part((uint32_t)(s * A_DIM + lane));
            float f = __uint_as_float(0x3f800000u | (bits >> 9)) - 1.0f;
            float u = fmaxf(f, 1.17549435e-38f);   // jnp.finfo(f32).tiny
            float g = -logf(-logf(u));
            z = lg + g;
        }
        int idx = lane;
#pragma unroll
        for (int o = 1; o < 64; o <<= 1) {
            float oz = __shfl_xor(z, o);
            int   oi = __shfl_xor(idx, o);
            if (oz > z || (oz == z && oi < idx)) { z = oz; idx = oi; }
        }

        float mx = lg;
#pragma unroll
        for (int o = 1; o < 64; o <<= 1) mx = fmaxf(mx, __shfl_xor(mx, o));
        float e = (lane < A_DIM) ? expf(lg - mx) : 0.f;
#pragma unroll
        for (int o = 1; o < 64; o <<= 1) e += __shfl_xor(e, o);
        float lse = mx + logf(e);
        float lp = lg - lse;
        float c = (lane < A_DIM) ? expf(lp) * lp : 0.f;
#pragma unroll
        for (int o = 1; o < 64; o <<= 1) c += __shfl_xor(c, o);

        if (active && lane == 0) {
            out[s]             = (float)idx;                 // action
            out[B_N + s]       = logits_lds[wv][idx] - lse;  // log_prob
            out[2 * B_N + s]   = -c;                         // entropy
        }
        __syncthreads();   // logits/red reuse next round (uniform: K is block-uniform)
    }
}

extern "C" void kernel_launch(void* const* d_in, const int* in_sizes, int n_in,
                              void* d_out, int out_size, void* d_ws, size_t ws_size,
                              hipStream_t stream) {
    const float* xs      = (const float*)d_in[0];
    const int*   traw    = (const int*)d_in[1];   // int32 or int64 — detected on device
    const float* w1      = (const float*)d_in[2];
    const float* b1      = (const float*)d_in[3];
    const float* w2      = (const float*)d_in[4];
    const float* b2      = (const float*)d_in[5];
    float* out = (float*)d_out;
    char*  ws  = (char*)d_ws;

    const size_t meta_bytes = META_INTS * sizeof(int);               // 8 KB
    const size_t part_bytes = (size_t)B_N * H_DIM * sizeof(float);   // 2 MB per K-split partial

    int ksp = 4;
    if (ws_size < meta_bytes + 4 * part_bytes) ksp = 2;
    if (ws_size < meta_bytes + 2 * part_bytes) ksp = 1;

    int*   meta = (int*)ws;
    float* hpre = (float*)(ws + meta_bytes);

    bucket_kernel<<<1, 1024, 0, stream>>>(traw, meta);

    if (ksp == 4) {
        fc1_kernel<4><<<dim3(T_N * NSB, 2, 4), 256, 0, stream>>>(xs, w1, meta, hpre);
        head_kernel<4><<<dim3(T_N, NSB2), 256, 0, stream>>>(meta, hpre, b1, w2, b2, out);
    } else if (ksp == 2) {
        fc1_kernel<2><<<dim3(T_N * NSB, 2, 2), 256, 0, stream>>>(xs, w1, meta, hpre);
        head_kernel<2><<<dim3(T_N, NSB2), 256, 0, stream>>>(meta, hpre, b1, w2, b2, out);
    } else {
        fc1_kernel<1><<<dim3(T_N * NSB, 2, 1), 256, 0, stream>>>(xs, w1, meta, hpre);
        head_kernel<1><<<dim3(T_N, NSB2), 256, 0, stream>>>(meta, hpre, b1, w2, b2, out);
    }
}